// Round 6
// baseline (236.002 us; speedup 1.0000x reference)
//
#include <hip/hip_runtime.h>
#include <stdint.h>

// Problem constants
#define B_   8
#define S_   2047
#define L_   2048      // S+1 (CLS prepended)
#define H_   256       // HIDDEN
#define NH_  8
#define HD_  32
#define V_   32001     // VOCAB+1
#define NCH_ 64        // k3 chunks per b
#define TCH_ 32        // t per chunk (NCH_*TCH_ == L_)

__device__ __forceinline__ float b2f(unsigned short u) {
    union { uint32_t i; float f; } c; c.i = ((uint32_t)u) << 16; return c.f;
}
__device__ __forceinline__ unsigned short f2b(float f) {
    union { float f; uint32_t i; } c; c.f = f;
    uint32_t x = c.i;
    uint32_t r = (x + 0x7fffu + ((x >> 16) & 1u)) >> 16;
    return (unsigned short)r;
}
__device__ __forceinline__ float foldx(float a, int off) {
    return a + __shfl_xor(a, off, 64);
}
__device__ __forceinline__ float sel8(const float a[8], int j) {
    float v = a[0];
    v = (j == 1) ? a[1] : v;
    v = (j == 2) ? a[2] : v;
    v = (j == 3) ? a[3] : v;
    v = (j == 4) ? a[4] : v;
    v = (j == 5) ? a[5] : v;
    v = (j == 6) ? a[6] : v;
    v = (j == 7) ? a[7] : v;
    return v;
}

// ---------------------------------------------------------------------------
// K0 (grid 8, block per head n): y0 = emb[2]+pe[0]; q0[k] = wq[n,k,:]·y0;
// qk[n][h] = (sum_k q0[k]*wk[n,k,h]) / sqrt(32). Block n zeroes counters[n].
// ---------------------------------------------------------------------------
__global__ __launch_bounds__(256) void k0_prep(const float* __restrict__ emb,
                                               const float* __restrict__ wq,
                                               const float* __restrict__ wk,
                                               float* __restrict__ qk,
                                               float* __restrict__ y0,
                                               int* __restrict__ counters) {
    __shared__ float y0_l[H_];
    __shared__ float q0p[HD_][8];
    __shared__ float q0_l[HD_];
    int n = blockIdx.x, tid = threadIdx.x;
    if (tid == 0) counters[n] = 0;
    float v = emb[2 * H_ + tid] + ((tid & 1) ? 1.0f : 0.0f);  // pe[0]: sin0/cos0
    y0_l[tid] = v;
    if (n == 0) y0[tid] = v;
    __syncthreads();
    {   // q0 partials: thread = (k, part); part covers 32 h
        int k = tid >> 3, part = tid & 7;
        const float* w = wq + (n * HD_ + k) * H_ + part * 32;
        const float* yy = y0_l + part * 32;
        float acc = 0.f;
#pragma unroll
        for (int j = 0; j < 32; ++j) acc += w[j] * yy[j];
        q0p[k][part] = acc;
    }
    __syncthreads();
    if (tid < HD_) {
        float s = 0.f;
#pragma unroll
        for (int j = 0; j < 8; ++j) s += q0p[tid][j];
        q0_l[tid] = s;
    }
    __syncthreads();
    float acc = 0.f;
    for (int k = 0; k < HD_; ++k)
        acc += q0_l[k] * wk[(n * HD_ + k) * H_ + tid];
    qk[n * H_ + tid] = acc * 0.17677669529663687f;  // 1/sqrt(32)
}

// ---------------------------------------------------------------------------
// K1 (grid 4096, wave = one (b,t) row; 16384 waves = 16 waves/SIMD):
// gather emb row + pe -> ycache (bf16); 8 score dots -> 17-shuffle fold ->
// E = exp(score) (no max-sub: |score| < 1) -> Et[b,t,n] (32B per wave).
// ---------------------------------------------------------------------------
__global__ __launch_bounds__(256) void k1_scores(const int* __restrict__ x,
                                                 const float* __restrict__ emb,
                                                 const float* __restrict__ qkw,
                                                 unsigned short* __restrict__ ycache,
                                                 float* __restrict__ Et) {
    int tid  = threadIdx.x;
    int lane = tid & 63;
    int gid  = blockIdx.x * 4 + (tid >> 6);   // (b,t) flat: 0..16383
    int b = gid >> 11, t = gid & (L_ - 1);
    int h0 = lane * 4;

    float4 qr[NH_];
#pragma unroll
    for (int n = 0; n < NH_; ++n)
        qr[n] = *(const float4*)(qkw + n * H_ + h0);

    // pe for h-pairs i0=lane*2, i1=lane*2+1 at position t
    const float cdiv = 0.07195578414202881f;  // ln(10000)/128
    float div0 = __expf(-(float)(lane * 2) * cdiv);
    float div1 = __expf(-(float)(lane * 2 + 1) * cdiv);
    float a0 = (float)t * div0, a1 = (float)t * div1;
    float s0 = __sinf(a0), c0 = __cosf(a0);
    float s1 = __sinf(a1), c1 = __cosf(a1);

    int tok = (t == 0) ? 2 : x[b * S_ + t - 1];
    float4 ev = *(const float4*)(emb + (size_t)tok * H_ + h0);
    float4 y4;
    y4.x = ev.x + s0; y4.y = ev.y + c0; y4.z = ev.z + s1; y4.w = ev.w + c1;
    ushort4 st;
    st.x = f2b(y4.x); st.y = f2b(y4.y); st.z = f2b(y4.z); st.w = f2b(y4.w);
    *(ushort4*)(ycache + ((size_t)gid << 8) + h0) = st;

    float a[NH_];
#pragma unroll
    for (int n = 0; n < NH_; ++n)
        a[n] = qr[n].x * y4.x + qr[n].y * y4.y + qr[n].z * y4.z + qr[n].w * y4.w;
    float m4[4];
#pragma unroll
    for (int k = 0; k < 4; ++k) {
        float lo = foldx(a[k], 32), hi = foldx(a[k + 4], 32);
        m4[k] = (lane & 32) ? hi : lo;
    }
    float m2[2];
#pragma unroll
    for (int k = 0; k < 2; ++k) {
        float lo = foldx(m4[k], 16), hi = foldx(m4[k + 2], 16);
        m2[k] = (lane & 16) ? hi : lo;
    }
    float lo = foldx(m2[0], 8), hi = foldx(m2[1], 8);
    float m1 = (lane & 8) ? hi : lo;
    m1 = foldx(m1, 4); m1 = foldx(m1, 2); m1 = foldx(m1, 1);
    float e = __expf(m1);
    if ((lane & 7) == 0)
        Et[(size_t)gid * NH_ + (lane >> 3)] = e;   // head = lane>>3 (verified R5)
}

// ---------------------------------------------------------------------------
// K3 (grid 512 = b*64+c, 32 t per chunk, thread = h): ybar psum partials
// (coalesced ushort y reads, E broadcast from LDS) + per-chunk esum.
// Last block per b: reduce psums+esums, normalize, wv & wo projections -> z.
// ---------------------------------------------------------------------------
__global__ __launch_bounds__(256) void k3_ybar(const float* __restrict__ Et,
                                               const unsigned short* __restrict__ ycache,
                                               const float* __restrict__ wv,
                                               const float* __restrict__ wo,
                                               const float* __restrict__ y0g,
                                               float* __restrict__ psum,
                                               float* __restrict__ esum_blk,
                                               float* __restrict__ z,
                                               int* __restrict__ counters) {
    int bid = blockIdx.x;              // b*64 + c
    int b = bid >> 6, c = bid & 63;
    int t0 = c * TCH_;
    int tid = threadIdx.x;

    __shared__ float e_l[TCH_ * NH_];  // 1 KB, [tt][n]
    __shared__ int is_last;
    __shared__ float inv_l[NH_];
    __shared__ float ybar_l[NH_ * 260];  // stride 260 breaks bank aliasing
    __shared__ float o_l[H_];

    e_l[tid] = Et[(size_t)(b * L_ + t0) * NH_ + tid];
    __syncthreads();
    if (tid < NH_) {
        float s = 0.f;
#pragma unroll
        for (int tt = 0; tt < TCH_; ++tt) s += e_l[tt * NH_ + tid];
        esum_blk[bid * NH_ + tid] = s;
    }

    // main: thread owns h = tid; accumulate 8 heads over 32 t
    float acc[NH_] = {};
    const unsigned short* yb = ycache + ((size_t)(b * L_ + t0) << 8) + tid;
#pragma unroll
    for (int tt = 0; tt < TCH_; ++tt) {
        float yv = b2f(yb[(size_t)tt << 8]);
        float4 eA = *(const float4*)&e_l[tt * NH_];
        float4 eB = *(const float4*)&e_l[tt * NH_ + 4];
        acc[0] += eA.x * yv; acc[1] += eA.y * yv;
        acc[2] += eA.z * yv; acc[3] += eA.w * yv;
        acc[4] += eB.x * yv; acc[5] += eB.y * yv;
        acc[6] += eB.z * yv; acc[7] += eB.w * yv;
    }
#pragma unroll
    for (int n = 0; n < NH_; ++n)
        psum[((size_t)bid * NH_ + n) * H_ + tid] = acc[n];

    // ---- last-block-per-b tail ----
    __threadfence();
    __syncthreads();
    if (tid == 0) is_last = (atomicAdd(&counters[b], 1) == NCH_ - 1);
    __syncthreads();
    if (!is_last) return;
    __threadfence();

    if (tid < NH_) {
        float s = 0.f;
#pragma unroll 8
        for (int cc = 0; cc < NCH_; ++cc)
            s += esum_blk[(b * NCH_ + cc) * NH_ + tid];
        inv_l[tid] = 1.0f / s;
    }
    __syncthreads();
#pragma unroll
    for (int n = 0; n < NH_; ++n) {
        const float* pp = psum + ((size_t)(b * NCH_) * NH_ + n) * H_ + tid;
        float s = 0.f;
#pragma unroll 8
        for (int cc = 0; cc < NCH_; ++cc) s += pp[(size_t)cc * NH_ * H_];
        ybar_l[n * 260 + tid] = s * inv_l[n];
    }
    __syncthreads();
    {   // o[j] = wv[j,:]·ybar[n(j),:]
        int n = tid >> 5;
        const float* wrow = wv + (size_t)tid * H_;
        const float* yy = ybar_l + n * 260;
        float s = 0.f;
#pragma unroll 16
        for (int h4 = 0; h4 < H_ / 4; ++h4) {
            float4 w4 = *(const float4*)(wrow + h4 * 4);
            float4 p4 = *(const float4*)(yy + h4 * 4);
            s += w4.x * p4.x + w4.y * p4.y + w4.z * p4.z + w4.w * p4.w;
        }
        o_l[tid] = s;
    }
    __syncthreads();
    {   // z[b,i] = wo[i,:]·o + 2*y0[i]
        const float* wrow = wo + (size_t)tid * H_;
        float s = 0.f;
#pragma unroll 16
        for (int j4 = 0; j4 < H_ / 4; ++j4) {
            float4 w4 = *(const float4*)(wrow + j4 * 4);
            s += w4.x * o_l[j4 * 4] + w4.y * o_l[j4 * 4 + 1]
               + w4.z * o_l[j4 * 4 + 2] + w4.w * o_l[j4 * 4 + 3];
        }
        z[b * H_ + tid] = s + 2.0f * y0g[tid];
    }
}

// ---------------------------------------------------------------------------
// K5 (grid 501): out[b,v] = z[b,:]·wu[v,:]. 16-lane groups own 16-h spans;
// 4 rows per pass per wave -> 8 shuffles/row.
// ---------------------------------------------------------------------------
__global__ __launch_bounds__(256) void k5_out(const float* __restrict__ z,
                                              const float* __restrict__ wu,
                                              float* __restrict__ out) {
    int tid = threadIdx.x, lane = tid & 63, w = tid >> 6;
    int m = lane & 15;
    int g = lane >> 4;
    int hb = m * 16;
    float zr[B_][16];
#pragma unroll
    for (int b = 0; b < B_; ++b)
#pragma unroll
        for (int jj = 0; jj < 4; ++jj)
            *(float4*)&zr[b][jj * 4] = *(const float4*)(z + b * H_ + hb + jj * 4);

    __shared__ float o_l[B_ * 65];
    int base = blockIdx.x * 64;
#pragma unroll
    for (int pass = 0; pass < 4; ++pass) {
        int rl = w * 16 + pass * 4 + g;
        int v = base + rl;
        int vc = (v < V_) ? v : (V_ - 1);
        const float* wr = wu + (size_t)vc * H_ + hb;
        float4 w0 = *(const float4*)(wr);
        float4 w1 = *(const float4*)(wr + 4);
        float4 w2 = *(const float4*)(wr + 8);
        float4 w3 = *(const float4*)(wr + 12);
        float acc[B_];
#pragma unroll
        for (int b = 0; b < B_; ++b) {
            acc[b] = zr[b][0] * w0.x + zr[b][1] * w0.y + zr[b][2] * w0.z + zr[b][3] * w0.w
                   + zr[b][4] * w1.x + zr[b][5] * w1.y + zr[b][6] * w1.z + zr[b][7] * w1.w
                   + zr[b][8] * w2.x + zr[b][9] * w2.y + zr[b][10] * w2.z + zr[b][11] * w2.w
                   + zr[b][12] * w3.x + zr[b][13] * w3.y + zr[b][14] * w3.z + zr[b][15] * w3.w;
        }
#pragma unroll
        for (int off = 1; off <= 8; off <<= 1) {
#pragma unroll
            for (int b = 0; b < B_; ++b) acc[b] += __shfl_xor(acc[b], off, 64);
        }
        if (m < B_) o_l[m * 65 + rl] = sel8(acc, m);
    }
    __syncthreads();
    for (int i = tid; i < B_ * 64; i += 256) {
        int b = i >> 6, vl = i & 63, v = base + vl;
        if (v < V_) out[b * V_ + v] = o_l[b * 65 + vl];
    }
}

// ---------------------------------------------------------------------------
extern "C" void kernel_launch(void* const* d_in, const int* in_sizes, int n_in,
                              void* d_out, int out_size, void* d_ws, size_t ws_size,
                              hipStream_t stream) {
    const int*   x   = (const int*)d_in[0];
    const float* emb = (const float*)d_in[1];
    const float* wq  = (const float*)d_in[2];
    const float* wk  = (const float*)d_in[3];
    const float* wv  = (const float*)d_in[4];
    const float* wo  = (const float*)d_in[5];
    const float* wu  = (const float*)d_in[6];
    float*       out = (float*)d_out;

    // ws layout (floats unless noted), ~13 MiB total:
    // qk[2048] | y0[256] | z[2048] | esum_blk[4096] | psum[512*8*256]
    // | Et[16384*8] | counters[16 ints] | ycache[16384*256 ushort]
    float* qk       = (float*)d_ws;
    float* y0       = qk + NH_ * H_;
    float* z        = y0 + H_;
    float* esum_blk = z + B_ * H_;
    float* psum     = esum_blk + 512 * NH_;
    float* Et       = psum + (size_t)512 * NH_ * H_;
    int*   counters = (int*)(Et + (size_t)B_ * L_ * NH_);
    unsigned short* ycache = (unsigned short*)(counters + 16);

    k0_prep  <<<8,    256, 0, stream>>>(emb, wq, wk, qk, y0, counters);
    k1_scores<<<4096, 256, 0, stream>>>(x, emb, qk, ycache, Et);
    k3_ybar  <<<512,  256, 0, stream>>>(Et, ycache, wv, wo, y0, psum, esum_blk, z, counters);
    k5_out   <<<(V_ + 63) / 64, 256, 0, stream>>>(z, wu, out);
}

// Round 7
// 163.865 us; speedup vs baseline: 1.4402x; 1.4402x over previous
//
#include <hip/hip_runtime.h>
#include <stdint.h>

// Problem constants
#define B_   8
#define S_   2047
#define L_   2048      // S+1 (CLS prepended)
#define H_   256       // HIDDEN
#define NH_  8
#define HD_  32
#define V_   32001     // VOCAB+1
#define NCH_ 64        // k3 chunks per b
#define TCH_ 32        // t per chunk (NCH_*TCH_ == L_)

__device__ __forceinline__ float b2f(unsigned short u) {
    union { uint32_t i; float f; } c; c.i = ((uint32_t)u) << 16; return c.f;
}
__device__ __forceinline__ unsigned short f2b(float f) {
    union { float f; uint32_t i; } c; c.f = f;
    uint32_t x = c.i;
    uint32_t r = (x + 0x7fffu + ((x >> 16) & 1u)) >> 16;
    return (unsigned short)r;
}
__device__ __forceinline__ float foldx(float a, int off) {
    return a + __shfl_xor(a, off, 64);
}
__device__ __forceinline__ float sel8(const float a[8], int j) {
    float v = a[0];
    v = (j == 1) ? a[1] : v;
    v = (j == 2) ? a[2] : v;
    v = (j == 3) ? a[3] : v;
    v = (j == 4) ? a[4] : v;
    v = (j == 5) ? a[5] : v;
    v = (j == 6) ? a[6] : v;
    v = (j == 7) ? a[7] : v;
    return v;
}

// ---------------------------------------------------------------------------
// K0 (grid 8, block per head n): y0 = emb[2]+pe[0]; q0[k] = wq[n,k,:]·y0;
// qk[n][h] = (sum_k q0[k]*wk[n,k,h]) / sqrt(32)
// ---------------------------------------------------------------------------
__global__ __launch_bounds__(256) void k0_prep(const float* __restrict__ emb,
                                               const float* __restrict__ wq,
                                               const float* __restrict__ wk,
                                               float* __restrict__ qk,
                                               float* __restrict__ y0) {
    __shared__ float y0_l[H_];
    __shared__ float q0p[HD_][8];
    __shared__ float q0_l[HD_];
    int n = blockIdx.x, tid = threadIdx.x;
    float v = emb[2 * H_ + tid] + ((tid & 1) ? 1.0f : 0.0f);  // pe[0]: sin0/cos0
    y0_l[tid] = v;
    if (n == 0) y0[tid] = v;
    __syncthreads();
    {   // q0 partials: thread = (k, part); part covers 32 h
        int k = tid >> 3, part = tid & 7;
        const float* w = wq + (n * HD_ + k) * H_ + part * 32;
        const float* yy = y0_l + part * 32;
        float acc = 0.f;
#pragma unroll
        for (int j = 0; j < 32; ++j) acc += w[j] * yy[j];
        q0p[k][part] = acc;
    }
    __syncthreads();
    if (tid < HD_) {
        float s = 0.f;
#pragma unroll
        for (int j = 0; j < 8; ++j) s += q0p[tid][j];
        q0_l[tid] = s;
    }
    __syncthreads();
    float acc = 0.f;
    for (int k = 0; k < HD_; ++k)
        acc += q0_l[k] * wk[(n * HD_ + k) * H_ + tid];
    qk[n * H_ + tid] = acc * 0.17677669529663687f;  // 1/sqrt(32)
}

// ---------------------------------------------------------------------------
// K1 (grid 4096, wave = one (b,t) row; 16384 waves):
// gather emb row + pe -> ycache (bf16); 8 score dots -> 17-shuffle fold ->
// E = exp(score) (no max-sub: |score| < 1) -> Et[b,t,n].
// ---------------------------------------------------------------------------
__global__ __launch_bounds__(256) void k1_scores(const int* __restrict__ x,
                                                 const float* __restrict__ emb,
                                                 const float* __restrict__ qkw,
                                                 unsigned short* __restrict__ ycache,
                                                 float* __restrict__ Et) {
    int tid  = threadIdx.x;
    int lane = tid & 63;
    int gid  = blockIdx.x * 4 + (tid >> 6);   // (b,t) flat: 0..16383
    int b = gid >> 11, t = gid & (L_ - 1);
    int h0 = lane * 4;

    float4 qr[NH_];
#pragma unroll
    for (int n = 0; n < NH_; ++n)
        qr[n] = *(const float4*)(qkw + n * H_ + h0);

    // pe for h-pairs i0=lane*2, i1=lane*2+1 at position t
    const float cdiv = 0.07195578414202881f;  // ln(10000)/128
    float div0 = __expf(-(float)(lane * 2) * cdiv);
    float div1 = __expf(-(float)(lane * 2 + 1) * cdiv);
    float a0 = (float)t * div0, a1 = (float)t * div1;
    float s0 = __sinf(a0), c0 = __cosf(a0);
    float s1 = __sinf(a1), c1 = __cosf(a1);

    int tok = (t == 0) ? 2 : x[b * S_ + t - 1];
    float4 ev = *(const float4*)(emb + (size_t)tok * H_ + h0);
    float4 y4;
    y4.x = ev.x + s0; y4.y = ev.y + c0; y4.z = ev.z + s1; y4.w = ev.w + c1;
    ushort4 st;
    st.x = f2b(y4.x); st.y = f2b(y4.y); st.z = f2b(y4.z); st.w = f2b(y4.w);
    *(ushort4*)(ycache + ((size_t)gid << 8) + h0) = st;

    float a[NH_];
#pragma unroll
    for (int n = 0; n < NH_; ++n)
        a[n] = qr[n].x * y4.x + qr[n].y * y4.y + qr[n].z * y4.z + qr[n].w * y4.w;
    float m4[4];
#pragma unroll
    for (int k = 0; k < 4; ++k) {
        float lo = foldx(a[k], 32), hi = foldx(a[k + 4], 32);
        m4[k] = (lane & 32) ? hi : lo;
    }
    float m2[2];
#pragma unroll
    for (int k = 0; k < 2; ++k) {
        float lo = foldx(m4[k], 16), hi = foldx(m4[k + 2], 16);
        m2[k] = (lane & 16) ? hi : lo;
    }
    float lo = foldx(m2[0], 8), hi = foldx(m2[1], 8);
    float m1 = (lane & 8) ? hi : lo;
    m1 = foldx(m1, 4); m1 = foldx(m1, 2); m1 = foldx(m1, 1);
    float e = __expf(m1);
    if ((lane & 7) == 0)
        Et[(size_t)gid * NH_ + (lane >> 3)] = e;
}

// ---------------------------------------------------------------------------
// K3 (grid 512 = b*64+c, 32 t per chunk, thread = h): ybar psum partials
// (coalesced ushort y reads, E broadcast from LDS) + per-chunk esum.
// NO tail, NO fences, NO atomics — pure streaming.
// ---------------------------------------------------------------------------
__global__ __launch_bounds__(256) void k3_ybar(const float* __restrict__ Et,
                                               const unsigned short* __restrict__ ycache,
                                               float* __restrict__ psum,
                                               float* __restrict__ esum_blk) {
    int bid = blockIdx.x;              // b*64 + c
    int b = bid >> 6, c = bid & 63;
    int t0 = c * TCH_;
    int tid = threadIdx.x;

    __shared__ float e_l[TCH_ * NH_];  // 1 KB, [tt][n]
    e_l[tid] = Et[(size_t)(b * L_ + t0) * NH_ + tid];
    __syncthreads();
    if (tid < NH_) {
        float s = 0.f;
#pragma unroll
        for (int tt = 0; tt < TCH_; ++tt) s += e_l[tt * NH_ + tid];
        esum_blk[bid * NH_ + tid] = s;
    }

    // main: thread owns h = tid; accumulate 8 heads over 32 t
    float acc[NH_] = {};
    const unsigned short* yb = ycache + ((size_t)(b * L_ + t0) << 8) + tid;
#pragma unroll
    for (int tt = 0; tt < TCH_; ++tt) {
        float yv = b2f(yb[(size_t)tt << 8]);
        float4 eA = *(const float4*)&e_l[tt * NH_];
        float4 eB = *(const float4*)&e_l[tt * NH_ + 4];
        acc[0] += eA.x * yv; acc[1] += eA.y * yv;
        acc[2] += eA.z * yv; acc[3] += eA.w * yv;
        acc[4] += eB.x * yv; acc[5] += eB.y * yv;
        acc[6] += eB.z * yv; acc[7] += eB.w * yv;
    }
#pragma unroll
    for (int n = 0; n < NH_; ++n)
        psum[((size_t)bid * NH_ + n) * H_ + tid] = acc[n];
}

// ---------------------------------------------------------------------------
// K4 (grid 64 = (b,n)): reduce esum + psum over 64 chunks -> ybar (normalized)
// -> wv projection -> o_g[b, n*32..+32]
// ---------------------------------------------------------------------------
__global__ __launch_bounds__(256) void k4_heads(const float* __restrict__ psum,
                                                const float* __restrict__ esum_blk,
                                                const float* __restrict__ wv,
                                                float* __restrict__ o_g) {
    int bid = blockIdx.x; int b = bid >> 3, n = bid & 7;
    int tid = threadIdx.x;
    __shared__ float inv_s;
    __shared__ float ybar_l[H_];
    __shared__ float op[HD_][8];
    if (tid < 64) {
        float v = esum_blk[(b * NCH_ + tid) * NH_ + n];
#pragma unroll
        for (int off = 32; off > 0; off >>= 1) v += __shfl_xor(v, off, 64);
        if (tid == 0) inv_s = 1.0f / v;
    }
    __syncthreads();
    {
        const float* pp = psum + ((size_t)(b * NCH_) * NH_ + n) * H_ + tid;
        float s = 0.f;
#pragma unroll 8
        for (int cc = 0; cc < NCH_; ++cc) s += pp[(size_t)cc * NH_ * H_];
        ybar_l[tid] = s * inv_s;
    }
    __syncthreads();
    {   // o[n*32+k] partial dots: thread = (k, p)
        int k = tid >> 3, p = tid & 7;
        const float* wrow = wv + (size_t)(n * HD_ + k) * H_ + p * 32;
        const float* yy = ybar_l + p * 32;
        float s = 0.f;
#pragma unroll
        for (int j = 0; j < 32; ++j) s += wrow[j] * yy[j];
        op[k][p] = s;
    }
    __syncthreads();
    if (tid < HD_) {
        float s = 0.f;
#pragma unroll
        for (int p = 0; p < 8; ++p) s += op[tid][p];
        o_g[b * (NH_ * HD_) + n * HD_ + tid] = s;
    }
}

// ---------------------------------------------------------------------------
// K4b (grid 8): z[b,i] = wo[i,:]·o[b,:] + 2*y0[i]
// ---------------------------------------------------------------------------
__global__ __launch_bounds__(256) void k4b_z(const float* __restrict__ o_g,
                                             const float* __restrict__ wo,
                                             const float* __restrict__ y0,
                                             float* __restrict__ z) {
    int b = blockIdx.x, tid = threadIdx.x;
    __shared__ float o_l[NH_ * HD_];
    o_l[tid] = o_g[b * (NH_ * HD_) + tid];
    __syncthreads();
    const float* wrow = wo + (size_t)tid * (NH_ * HD_);
    float s = 0.f;
#pragma unroll 16
    for (int j4 = 0; j4 < (NH_ * HD_) / 4; ++j4) {
        float4 w4 = *(const float4*)(wrow + j4 * 4);
        s += w4.x * o_l[j4 * 4] + w4.y * o_l[j4 * 4 + 1]
           + w4.z * o_l[j4 * 4 + 2] + w4.w * o_l[j4 * 4 + 3];
    }
    z[b * H_ + tid] = s + 2.0f * y0[tid];
}

// ---------------------------------------------------------------------------
// K5 (grid 501): out[b,v] = z[b,:]·wu[v,:]. 16-lane groups own 16-h spans;
// 4 rows per pass per wave -> 8 shuffles/row.
// ---------------------------------------------------------------------------
__global__ __launch_bounds__(256) void k5_out(const float* __restrict__ z,
                                              const float* __restrict__ wu,
                                              float* __restrict__ out) {
    int tid = threadIdx.x, lane = tid & 63, w = tid >> 6;
    int m = lane & 15;
    int g = lane >> 4;
    int hb = m * 16;
    float zr[B_][16];
#pragma unroll
    for (int b = 0; b < B_; ++b)
#pragma unroll
        for (int jj = 0; jj < 4; ++jj)
            *(float4*)&zr[b][jj * 4] = *(const float4*)(z + b * H_ + hb + jj * 4);

    __shared__ float o_l[B_ * 65];
    int base = blockIdx.x * 64;
#pragma unroll
    for (int pass = 0; pass < 4; ++pass) {
        int rl = w * 16 + pass * 4 + g;
        int v = base + rl;
        int vc = (v < V_) ? v : (V_ - 1);
        const float* wr = wu + (size_t)vc * H_ + hb;
        float4 w0 = *(const float4*)(wr);
        float4 w1 = *(const float4*)(wr + 4);
        float4 w2 = *(const float4*)(wr + 8);
        float4 w3 = *(const float4*)(wr + 12);
        float acc[B_];
#pragma unroll
        for (int b = 0; b < B_; ++b) {
            acc[b] = zr[b][0] * w0.x + zr[b][1] * w0.y + zr[b][2] * w0.z + zr[b][3] * w0.w
                   + zr[b][4] * w1.x + zr[b][5] * w1.y + zr[b][6] * w1.z + zr[b][7] * w1.w
                   + zr[b][8] * w2.x + zr[b][9] * w2.y + zr[b][10] * w2.z + zr[b][11] * w2.w
                   + zr[b][12] * w3.x + zr[b][13] * w3.y + zr[b][14] * w3.z + zr[b][15] * w3.w;
        }
#pragma unroll
        for (int off = 1; off <= 8; off <<= 1) {
#pragma unroll
            for (int b = 0; b < B_; ++b) acc[b] += __shfl_xor(acc[b], off, 64);
        }
        if (m < B_) o_l[m * 65 + rl] = sel8(acc, m);
    }
    __syncthreads();
    for (int i = tid; i < B_ * 64; i += 256) {
        int b = i >> 6, vl = i & 63, v = base + vl;
        if (v < V_) out[b * V_ + v] = o_l[b * 65 + vl];
    }
}

// ---------------------------------------------------------------------------
extern "C" void kernel_launch(void* const* d_in, const int* in_sizes, int n_in,
                              void* d_out, int out_size, void* d_ws, size_t ws_size,
                              hipStream_t stream) {
    const int*   x   = (const int*)d_in[0];
    const float* emb = (const float*)d_in[1];
    const float* wq  = (const float*)d_in[2];
    const float* wk  = (const float*)d_in[3];
    const float* wv  = (const float*)d_in[4];
    const float* wo  = (const float*)d_in[5];
    const float* wu  = (const float*)d_in[6];
    float*       out = (float*)d_out;

    // ws layout (floats unless noted), ~14 MiB total:
    // qk[2048] | y0[256] | z[2048] | o_g[2048] | esum_blk[4096]
    // | psum[512*8*256] | Et[16384*8] | ycache[16384*256 ushort]
    float* qk       = (float*)d_ws;
    float* y0       = qk + NH_ * H_;
    float* z        = y0 + H_;
    float* o_g      = z + B_ * H_;
    float* esum_blk = o_g + NH_ * HD_ * B_;
    float* psum     = esum_blk + 512 * NH_;
    float* Et       = psum + (size_t)512 * NH_ * H_;
    unsigned short* ycache = (unsigned short*)(Et + (size_t)B_ * L_ * NH_);

    k0_prep  <<<8,    256, 0, stream>>>(emb, wq, wk, qk, y0);
    k1_scores<<<4096, 256, 0, stream>>>(x, emb, qk, ycache, Et);
    k3_ybar  <<<512,  256, 0, stream>>>(Et, ycache, psum, esum_blk);
    k4_heads <<<64,   256, 0, stream>>>(psum, esum_blk, wv, o_g);
    k4b_z    <<<8,    256, 0, stream>>>(o_g, wo, y0, z);
    k5_out   <<<(V_ + 63) / 64, 256, 0, stream>>>(z, wu, out);
}